// Round 2
// baseline (2862.640 us; speedup 1.0000x reference)
//
#include <hip/hip_runtime.h>
#include <cstdint>
#include <cstddef>

#define T_STEPS 1000
#define NS      512
#define HID     128
#define DOUT    20
#define XPAD    129   // x tile row pad (bank-conflict-free lane reads)
#define WPAD    129   // transposed-weight row pad (2 lanes/bank = conflict-free)

// ---------------------------------------------------------------------------
// Pass 0: dense precompute D[row][o] = dot(x_row, Wi1[o][:]) using the exact
// 4-accumulator stride-4 fmaf chain that was verified bit-exact vs numpy in
// round 1 (a_i sums k ≡ i mod 4 ascending; final (a0+a1)+(a2+a3)). DO NOT
// change this order: spike thresholds make the dynamics chaotic to 1-ulp flips.
// ---------------------------------------------------------------------------
extern "C" __global__ void __launch_bounds__(512, 1)
srnn_dense(const float* __restrict__ x, const float* __restrict__ Wi1,
           float* __restrict__ D, int t0, int Tc)
{
    extern __shared__ float sm[];
    float* xs = sm;                    // [128 rows][XPAD]
    float* Wl = sm + 128 * XPAD;       // Wi1 row-major [128][128]
    const int tid = threadIdx.x;
    const int w = tid >> 6, ln = tid & 63;
    const int rb = blockIdx.x * 128;   // chunk-row base

    for (int i = tid; i < HID * HID / 4; i += 512)
        ((float4*)Wl)[i] = ((const float4*)Wi1)[i];
    for (int i = tid; i < 128 * 32; i += 512) {
        int r = i >> 5, kq = i & 31;
        int cr = rb + r;
        int s = cr / Tc, trel = cr - s * Tc;     // chunk row -> (sample, t)
        float4 v = ((const float4*)x)[((size_t)s * T_STEPS + t0 + trel) * 32 + kq];
        float* dst = &xs[r * XPAD + 4 * kq];
        dst[0] = v.x; dst[1] = v.y; dst[2] = v.z; dst[3] = v.w;
    }
    __syncthreads();

    const float* xr0 = xs + ln * XPAD;
    const float* xr1 = xs + (64 + ln) * XPAD;
    for (int og = 0; og < 4; ++og) {
        const int o = 16 * w + 4 * og;
        float a[2][4][4];
        #pragma unroll
        for (int r = 0; r < 2; ++r)
            #pragma unroll
            for (int j = 0; j < 4; ++j)
                #pragma unroll
                for (int i = 0; i < 4; ++i) a[r][j][i] = 0.f;

        #pragma unroll 4
        for (int k = 0; k < HID; k += 4) {
            float4 wv[4];
            #pragma unroll
            for (int j = 0; j < 4; ++j)
                wv[j] = *(const float4*)&Wl[(o + j) * HID + k];   // wave-uniform b128
            float xa0[4], xa1[4];
            #pragma unroll
            for (int i = 0; i < 4; ++i) { xa0[i] = xr0[k + i]; xa1[i] = xr1[k + i]; }
            #pragma unroll
            for (int j = 0; j < 4; ++j) {
                a[0][j][0] = fmaf(xa0[0], wv[j].x, a[0][j][0]);
                a[0][j][1] = fmaf(xa0[1], wv[j].y, a[0][j][1]);
                a[0][j][2] = fmaf(xa0[2], wv[j].z, a[0][j][2]);
                a[0][j][3] = fmaf(xa0[3], wv[j].w, a[0][j][3]);
                a[1][j][0] = fmaf(xa1[0], wv[j].x, a[1][j][0]);
                a[1][j][1] = fmaf(xa1[1], wv[j].y, a[1][j][1]);
                a[1][j][2] = fmaf(xa1[2], wv[j].z, a[1][j][2]);
                a[1][j][3] = fmaf(xa1[3], wv[j].w, a[1][j][3]);
            }
        }
        #pragma unroll
        for (int r = 0; r < 2; ++r) {
            float4 dv;
            dv.x = (a[r][0][0] + a[r][0][1]) + (a[r][0][2] + a[r][0][3]);
            dv.y = (a[r][1][0] + a[r][1][1]) + (a[r][1][2] + a[r][1][3]);
            dv.z = (a[r][2][0] + a[r][2][1]) + (a[r][2][2] + a[r][2][3]);
            dv.w = (a[r][3][0] + a[r][3][1]) + (a[r][3][2] + a[r][3][3]);
            *(float4*)&D[(size_t)(rb + 64 * r + ln) * HID + o] = dv;
        }
    }
}

// ---------------------------------------------------------------------------
// Uniformity helper: force a 64-bit mask into SGPRs so the whole bit-walk
// (ctz / clear-lowest / popcnt / selects) compiles to SALU, running in
// parallel with the VALU+LDS pipe. Any mask loaded from MEMORY must pass
// through this before entering the loop-carried mask phi, or divergence
// analysis demotes the entire chain to 64-bit VALU ops (round-1 regression:
// VALUBusy 7.5%->23%, layer2 520->934 us).
// ---------------------------------------------------------------------------
__device__ __forceinline__ unsigned long long rfl64(unsigned long long v)
{
    unsigned int lo = (unsigned int)__builtin_amdgcn_readfirstlane((int)(v & 0xffffffffULL));
    unsigned int hi = (unsigned int)__builtin_amdgcn_readfirstlane((int)(v >> 32));
    return ((unsigned long long)hi << 32) | (unsigned long long)lo;
}

// Branchless ascending 128-bit bit-walker. Returns next set-bit index
// (m0 bits 0..63 first, then m1 as 64..127) or 128 when exhausted.
// Index 128 points at a zeroed LDS row -> fold adds exact +0.0 at the END
// of the ascending chain (identity; bit-exact; harness-validated).
__device__ __forceinline__ int next128z(unsigned long long& lo, unsigned long long& hi)
{
    unsigned long long l = lo, h = hi;
    int jl = (int)__builtin_ctzll(l | 0x8000000000000000ULL);
    int jh = (int)__builtin_ctzll(h | 0x8000000000000000ULL);
    int j  = l ? jl : (h ? 64 + jh : 128);
    lo = l & (l - 1);
    hi = l ? h : (h & (h - 1));
    return j;
}

// Batched sparse walk over one [129][WPAD] table: extract up to 8 ascending
// indices (SALU), issue all 16 ds_read_b32 back-to-back (in-order return ->
// counted lgkmcnt overlaps fold with outstanding reads), then fold ascending.
__device__ __forceinline__ void walk8(const float* __restrict__ WT, int ln,
                                      unsigned long long m0, unsigned long long m1,
                                      float& rl, float& rh)
{
    unsigned long long lo = m0, hi = m1;
    int n = __popcll(m0) + __popcll(m1);
    while (n > 0) {                           // wave-uniform trip count
        int jj[8];
        #pragma unroll
        for (int u = 0; u < 8; ++u) jj[u] = next128z(lo, hi);
        float va[8], vb[8];
        #pragma unroll
        for (int u = 0; u < 8; ++u) {
            const float* p = WT + jj[u] * WPAD + ln;
            va[u] = p[0];                     // ds_read_b32
            vb[u] = p[64];                    // ds_read_b32 offset:256
        }
        #pragma unroll
        for (int u = 0; u < 8; ++u) { rl += va[u]; rh += vb[u]; }
        n -= 8;
    }
}

// Stage [o][j] row-major 128x128 weight matrix into transposed LDS table
// WT[j*WPAD + o] = W[o][j], plus zeroed dummy row j=128.
__device__ __forceinline__ void stage_wt(float* WT, const float* __restrict__ W, int tid)
{
    for (int i = tid; i < HID * HID / 4; i += 128) {
        int o = i >> 5, jq = i & 31;
        float4 v = ((const float4*)W)[i];
        WT[(4 * jq + 0) * WPAD + o] = v.x;
        WT[(4 * jq + 1) * WPAD + o] = v.y;
        WT[(4 * jq + 2) * WPAD + o] = v.z;
        WT[(4 * jq + 3) * WPAD + o] = v.w;
    }
    for (int i = tid; i < WPAD; i += 128) WT[128 * WPAD + i] = 0.f;
}

// ---------------------------------------------------------------------------
// Pass 1: layer-1 recurrence. One wave per sample; lane ln owns neurons
// {ln, 64+ln}. Spike masks live in SGPRs via ballots (state init forced
// uniform with readfirstlane) -> SALU extraction, batched LDS reads.
// ---------------------------------------------------------------------------
extern "C" __global__ void __launch_bounds__(128, 1)
srnn_layer1(const float* __restrict__ D, const float* __restrict__ Wh1,
            const float* __restrict__ bi1, const float* __restrict__ bh1,
            ulonglong2* __restrict__ masks, ulonglong2* __restrict__ state,
            int t0, int Tc, int first)
{
    extern __shared__ float WT[];      // [129][WPAD]
    const int tid = threadIdx.x, w = tid >> 6, ln = tid & 63;
    const int s = 2 * blockIdx.x + w;

    stage_wt(WT, Wh1, tid);

    const float bil = bi1[ln], bih = bi1[64 + ln];
    const float bhl = bh1[ln], bhh = bh1[64 + ln];
    unsigned long long m0 = 0ULL, m1 = 0ULL;
    if (!first) {
        ulonglong2 st = state[s];
        m0 = rfl64(st.x); m1 = rfl64(st.y);    // keep mask phi uniform (SALU)
    }

    const float* Drow = D + (size_t)s * Tc * HID;
    float dl[8], dh[8];
    #pragma unroll
    for (int p = 0; p < 8; ++p) {
        int ti = p < Tc ? p : Tc - 1;
        dl[p] = Drow[ti * HID + ln];
        dh[p] = Drow[ti * HID + 64 + ln];
    }
    __syncthreads();

    for (int tt = 0; tt < Tc; tt += 8) {
        #pragma unroll
        for (int u = 0; u < 8; ++u) {
            int t = tt + u;
            if (t >= Tc) break;                       // wave-uniform
            float dense_l = dl[u], dense_h = dh[u];
            int tp = (t + 8 < Tc) ? t + 8 : Tc - 1;   // clamped prefetch
            dl[u] = Drow[tp * HID + ln];
            dh[u] = Drow[tp * HID + 64 + ln];

            float rl = 0.f, rh = 0.f;                 // ascending-j, bit-exact
            walk8(WT, ln, m0, m1, rl, rh);

            float hl = ((dense_l + bil) + rl) + bhl;  // reference add order
            float hh = ((dense_h + bih) + rh) + bhh;
            m0 = __ballot(hl >= 1.0f);
            m1 = __ballot(hh >= 1.0f);
            if (ln == 0) {
                ulonglong2 mv; mv.x = m0; mv.y = m1;
                masks[(size_t)s * T_STEPS + (t0 + t)] = mv;
            }
        }
    }
    if (ln == 0) { ulonglong2 st; st.x = m0; st.y = m1; state[s] = st; }
}

// ---------------------------------------------------------------------------
// Pass 2: layer-2 recurrence + output accumulation. Fully sparse; masks in
// SGPRs (prefetched s1 masks forced uniform at use). WI and WH walks are
// independent (s1 prefetched, p from previous step) -> hand-fused batch loop
// so both batches' loads are in flight under one LDS latency.
// ---------------------------------------------------------------------------
extern "C" __global__ void __launch_bounds__(128, 1)
srnn_layer2(const ulonglong2* __restrict__ masks,
            const float* __restrict__ Wi2, const float* __restrict__ bi2,
            const float* __restrict__ Wh2, const float* __restrict__ bh2,
            const float* __restrict__ Wo,  const float* __restrict__ bo,
            float* __restrict__ out)
{
    extern __shared__ float sm2[];
    float* WI  = sm2;                       // Wi2^T [129][WPAD] (row 128 = 0)
    float* WH  = sm2 + 129 * WPAD;          // Wh2^T [129][WPAD] (row 128 = 0)
    float* WOt = sm2 + 2 * 129 * WPAD;      // Wo^T  [129][DOUT] (row 128 = 0)
    const int tid = threadIdx.x, w = tid >> 6, ln = tid & 63;
    const int s = 2 * blockIdx.x + w;

    stage_wt(WI, Wi2, tid);
    stage_wt(WH, Wh2, tid);
    for (int i = tid; i < DOUT * HID / 4; i += 128) {
        int o = i >> 5, jq = i & 31;
        float4 v = ((const float4*)Wo)[i];
        WOt[(4 * jq + 0) * DOUT + o] = v.x; WOt[(4 * jq + 1) * DOUT + o] = v.y;
        WOt[(4 * jq + 2) * DOUT + o] = v.z; WOt[(4 * jq + 3) * DOUT + o] = v.w;
    }
    for (int i = tid; i < DOUT; i += 128) WOt[128 * DOUT + i] = 0.f;

    const float bil = bi2[ln], bih = bi2[64 + ln];
    const float bhl = bh2[ln], bhh = bh2[64 + ln];
    const bool  oth = (ln < DOUT);
    const float bol = oth ? bo[ln] : 0.f;

    const ulonglong2* mrow = masks + (size_t)s * T_STEPS;
    ulonglong2 mb[8];
    #pragma unroll
    for (int p = 0; p < 8; ++p) mb[p] = mrow[p];
    unsigned long long p0 = 0ULL, p1 = 0ULL;
    float acc = 0.f;
    __syncthreads();

    for (int tt = 0; tt < T_STEPS; tt += 8) {
        #pragma unroll
        for (int u = 0; u < 8; ++u) {
            int t = tt + u;
            ulonglong2 s1 = mb[u];
            int tp = (t + 8 < T_STEPS) ? t + 8 : T_STEPS - 1;
            mb[u] = mrow[tp];

            // force prefetched masks uniform -> SALU extraction
            unsigned long long la = rfl64(s1.x), ha = rfl64(s1.y);
            unsigned long long lb = p0,          hb = p1;   // ballot-native uniform
            int nA = __popcll(la) + __popcll(ha);
            int nB = __popcll(lb) + __popcll(hb);
            int n  = nA > nB ? nA : nB;

            float Al = 0.f, Ah = 0.f;                 // s1 @ Wi2^T (ascending)
            float Bl = 0.f, Bh = 0.f;                 // s2 @ Wh2^T (ascending)
            while (n > 0) {                           // fused dual batch
                int ja[8], jb[8];
                #pragma unroll
                for (int v8 = 0; v8 < 8; ++v8) ja[v8] = next128z(la, ha);
                #pragma unroll
                for (int v8 = 0; v8 < 8; ++v8) jb[v8] = next128z(lb, hb);
                float aA[8], bA[8], aB[8], bB[8];
                #pragma unroll
                for (int v8 = 0; v8 < 8; ++v8) {
                    const float* p = WI + ja[v8] * WPAD + ln;
                    aA[v8] = p[0]; bA[v8] = p[64];
                }
                #pragma unroll
                for (int v8 = 0; v8 < 8; ++v8) {
                    const float* p = WH + jb[v8] * WPAD + ln;
                    aB[v8] = p[0]; bB[v8] = p[64];
                }
                #pragma unroll
                for (int v8 = 0; v8 < 8; ++v8) { Al += aA[v8]; Ah += bA[v8]; }
                #pragma unroll
                for (int v8 = 0; v8 < 8; ++v8) { Bl += aB[v8]; Bh += bB[v8]; }
                n -= 8;
            }

            float hl = ((Al + bil) + Bl) + bhl;       // reference add order
            float hh = ((Ah + bih) + Bh) + bhh;
            p0 = __ballot(hl >= 1.0f);
            p1 = __ballot(hh >= 1.0f);

            if (oth) {                                 // s2 @ Wo^T + bo
                float d = 0.f;
                unsigned long long lo = p0, hi = p1;
                int no = __popcll(p0) + __popcll(p1);
                while (no > 0) {
                    int jj[8];
                    #pragma unroll
                    for (int v8 = 0; v8 < 8; ++v8) jj[v8] = next128z(lo, hi);
                    float vv[8];
                    #pragma unroll
                    for (int v8 = 0; v8 < 8; ++v8) vv[v8] = WOt[jj[v8] * DOUT + ln];
                    #pragma unroll
                    for (int v8 = 0; v8 < 8; ++v8) d += vv[v8];
                    no -= 8;
                }
                acc += d;                              // (acc + dot) ...
                acc += bol;                            //  ... + bo
            }
        }
    }
    if (oth) out[s * DOUT + ln] = acc / (float)T_STEPS;
}

// ---------------------------------------------------------------------------
extern "C" void kernel_launch(void* const* d_in, const int* in_sizes, int n_in,
                              void* d_out, int out_size, void* d_ws, size_t ws_size,
                              hipStream_t stream) {
    const float* x   = (const float*)d_in[0];
    const float* Wi1 = (const float*)d_in[1];
    const float* bi1 = (const float*)d_in[2];
    const float* Wh1 = (const float*)d_in[3];
    const float* bh1 = (const float*)d_in[4];
    const float* Wi2 = (const float*)d_in[5];
    const float* bi2 = (const float*)d_in[6];
    const float* Wh2 = (const float*)d_in[7];
    const float* bh2 = (const float*)d_in[8];
    const float* Wo  = (const float*)d_in[9];
    const float* bo  = (const float*)d_in[10];
    float* out = (float*)d_out;

    // ws layout: [masks 8.192 MB][layer1 state 8 KB][D chunk buffer]
    const size_t mask_bytes  = (size_t)NS * T_STEPS * sizeof(ulonglong2);
    const size_t state_bytes = (size_t)NS * sizeof(ulonglong2);
    ulonglong2* masks = (ulonglong2*)d_ws;
    ulonglong2* state = (ulonglong2*)((char*)d_ws + mask_bytes);
    float* D = (float*)((char*)d_ws + mask_bytes + state_bytes);

    size_t avail = ws_size > mask_bytes + state_bytes
                 ? ws_size - mask_bytes - state_bytes : 0;
    const size_t bytes_per_t = (size_t)NS * HID * sizeof(float);  // 256 KB
    long tcmax = (long)(avail / bytes_per_t);
    static const int divs[] = {1000, 500, 250, 200, 125, 100, 50, 40, 25, 20, 10, 8, 5, 4, 2, 1};
    int Tc = 1;
    for (int i = 0; i < 16; ++i) if (divs[i] <= tcmax) { Tc = divs[i]; break; }

    const int lds0 = (128 * XPAD + HID * HID) * (int)sizeof(float);
    const int lds1 = (129 * WPAD) * (int)sizeof(float);
    const int lds2 = (2 * 129 * WPAD + 129 * DOUT) * (int)sizeof(float);
    hipFuncSetAttribute((const void*)srnn_dense,
                        hipFuncAttributeMaxDynamicSharedMemorySize, lds0);
    hipFuncSetAttribute((const void*)srnn_layer1,
                        hipFuncAttributeMaxDynamicSharedMemorySize, lds1);
    hipFuncSetAttribute((const void*)srnn_layer2,
                        hipFuncAttributeMaxDynamicSharedMemorySize, lds2);

    for (int t0 = 0; t0 < T_STEPS; t0 += Tc) {
        srnn_dense<<<4 * Tc, 512, lds0, stream>>>(x, Wi1, D, t0, Tc);
        srnn_layer1<<<NS / 2, 128, lds1, stream>>>(D, Wh1, bi1, bh1, masks, state,
                                                   t0, Tc, t0 == 0 ? 1 : 0);
    }
    srnn_layer2<<<NS / 2, 128, lds2, stream>>>(masks, Wi2, bi2, Wh2, bh2, Wo, bo, out);
}

// Round 3
// 2132.433 us; speedup vs baseline: 1.3424x; 1.3424x over previous
//
#include <hip/hip_runtime.h>
#include <cstdint>
#include <cstddef>

#define T_STEPS 1000
#define NS      512
#define HID     128
#define DOUT    20
#define XPAD    129   // x tile row pad (bank-conflict-free lane reads)
#define WPAD    129   // transposed-weight row pad (2 lanes/bank = conflict-free)

// ---------------------------------------------------------------------------
// Pass 0: dense precompute D[row][o] = dot(x_row, Wi1[o][:]) using the exact
// 4-accumulator stride-4 fmaf chain that was verified bit-exact vs numpy in
// round 1 (a_i sums k ≡ i mod 4 ascending; final (a0+a1)+(a2+a3)). DO NOT
// change this order: spike thresholds make the dynamics chaotic to 1-ulp flips.
// ---------------------------------------------------------------------------
extern "C" __global__ void __launch_bounds__(512, 1)
srnn_dense(const float* __restrict__ x, const float* __restrict__ Wi1,
           float* __restrict__ D, int t0, int Tc)
{
    extern __shared__ float sm[];
    float* xs = sm;                    // [128 rows][XPAD]
    float* Wl = sm + 128 * XPAD;       // Wi1 row-major [128][128]
    const int tid = threadIdx.x;
    const int w = tid >> 6, ln = tid & 63;
    const int rb = blockIdx.x * 128;   // chunk-row base

    for (int i = tid; i < HID * HID / 4; i += 512)
        ((float4*)Wl)[i] = ((const float4*)Wi1)[i];
    for (int i = tid; i < 128 * 32; i += 512) {
        int r = i >> 5, kq = i & 31;
        int cr = rb + r;
        int s = cr / Tc, trel = cr - s * Tc;     // chunk row -> (sample, t)
        float4 v = ((const float4*)x)[((size_t)s * T_STEPS + t0 + trel) * 32 + kq];
        float* dst = &xs[r * XPAD + 4 * kq];
        dst[0] = v.x; dst[1] = v.y; dst[2] = v.z; dst[3] = v.w;
    }
    __syncthreads();

    const float* xr0 = xs + ln * XPAD;
    const float* xr1 = xs + (64 + ln) * XPAD;
    for (int og = 0; og < 4; ++og) {
        const int o = 16 * w + 4 * og;
        float a[2][4][4];
        #pragma unroll
        for (int r = 0; r < 2; ++r)
            #pragma unroll
            for (int j = 0; j < 4; ++j)
                #pragma unroll
                for (int i = 0; i < 4; ++i) a[r][j][i] = 0.f;

        #pragma unroll 4
        for (int k = 0; k < HID; k += 4) {
            float4 wv[4];
            #pragma unroll
            for (int j = 0; j < 4; ++j)
                wv[j] = *(const float4*)&Wl[(o + j) * HID + k];   // wave-uniform b128
            float xa0[4], xa1[4];
            #pragma unroll
            for (int i = 0; i < 4; ++i) { xa0[i] = xr0[k + i]; xa1[i] = xr1[k + i]; }
            #pragma unroll
            for (int j = 0; j < 4; ++j) {
                a[0][j][0] = fmaf(xa0[0], wv[j].x, a[0][j][0]);
                a[0][j][1] = fmaf(xa0[1], wv[j].y, a[0][j][1]);
                a[0][j][2] = fmaf(xa0[2], wv[j].z, a[0][j][2]);
                a[0][j][3] = fmaf(xa0[3], wv[j].w, a[0][j][3]);
                a[1][j][0] = fmaf(xa1[0], wv[j].x, a[1][j][0]);
                a[1][j][1] = fmaf(xa1[1], wv[j].y, a[1][j][1]);
                a[1][j][2] = fmaf(xa1[2], wv[j].z, a[1][j][2]);
                a[1][j][3] = fmaf(xa1[3], wv[j].w, a[1][j][3]);
            }
        }
        #pragma unroll
        for (int r = 0; r < 2; ++r) {
            float4 dv;
            dv.x = (a[r][0][0] + a[r][0][1]) + (a[r][0][2] + a[r][0][3]);
            dv.y = (a[r][1][0] + a[r][1][1]) + (a[r][1][2] + a[r][1][3]);
            dv.z = (a[r][2][0] + a[r][2][1]) + (a[r][2][2] + a[r][2][3]);
            dv.w = (a[r][3][0] + a[r][3][1]) + (a[r][3][2] + a[r][3][3]);
            *(float4*)&D[(size_t)(rb + 64 * r + ln) * HID + o] = dv;
        }
    }
}

// ---------------------------------------------------------------------------
// Uniformity helper: force a 64-bit mask into SGPRs so all mask arithmetic
// stays SALU and branches on it are scalar.
// ---------------------------------------------------------------------------
__device__ __forceinline__ unsigned long long rfl64(unsigned long long v)
{
    unsigned int lo = (unsigned int)__builtin_amdgcn_readfirstlane((int)(v & 0xffffffffULL));
    unsigned int hi = (unsigned int)__builtin_amdgcn_readfirstlane((int)(v >> 32));
    return ((unsigned long long)hi << 32) | (unsigned long long)lo;
}

// Branchless ascending 128-bit bit-walker (dummy index 128 -> zeroed LDS row,
// exact +0.0 at END of ascending chain; harness-validated).
__device__ __forceinline__ int next128z(unsigned long long& lo, unsigned long long& hi)
{
    unsigned long long l = lo, h = hi;
    int jl = (int)__builtin_ctzll(l | 0x8000000000000000ULL);
    int jh = (int)__builtin_ctzll(h | 0x8000000000000000ULL);
    int j  = l ? jl : (h ? 64 + jh : 128);
    lo = l & (l - 1);
    hi = l ? h : (h & (h - 1));
    return j;
}

// Sparse gather-fold over a [129][WPAD] LDS table. Used ONLY in the
// high-occupancy dense2 pass (16 waves/CU) where per-wave LDS latency is
// hidden by TLP — NOT in the serial recurrence kernels (rounds 1-2 showed
// the compiler serializes load+add at 1-wave occupancy).
__device__ __forceinline__ void walk8(const float* __restrict__ WT, int ln,
                                      unsigned long long m0, unsigned long long m1,
                                      float& rl, float& rh)
{
    unsigned long long lo = m0, hi = m1;
    int n = __popcll(m0) + __popcll(m1);
    while (n > 0) {                           // wave-uniform trip count
        int jj[8];
        #pragma unroll
        for (int u = 0; u < 8; ++u) jj[u] = next128z(lo, hi);
        float va[8], vb[8];
        #pragma unroll
        for (int u = 0; u < 8; ++u) {
            const float* p = WT + jj[u] * WPAD + ln;
            va[u] = p[0];
            vb[u] = p[64];
        }
        #pragma unroll
        for (int u = 0; u < 8; ++u) { rl += va[u]; rh += vb[u]; }
        n -= 8;
    }
}

// Stage [o][j] row-major 128x128 weight matrix into transposed LDS table
// WT[j*WPAD + o] = W[o][j], plus zeroed dummy row j=128. Generic thread count.
__device__ __forceinline__ void stage_wt_s(float* WT, const float* __restrict__ W,
                                           int tid, int nthr)
{
    for (int i = tid; i < HID * HID / 4; i += nthr) {
        int o = i >> 5, jq = i & 31;
        float4 v = ((const float4*)W)[i];
        WT[(4 * jq + 0) * WPAD + o] = v.x;
        WT[(4 * jq + 1) * WPAD + o] = v.y;
        WT[(4 * jq + 2) * WPAD + o] = v.z;
        WT[(4 * jq + 3) * WPAD + o] = v.w;
    }
    for (int i = tid; i < WPAD; i += nthr) WT[128 * WPAD + i] = 0.f;
}

// ---------------------------------------------------------------------------
// Byte-skip register fold: rl/rh += sum over spiked j of wa[j]/wb[j], j
// ascending. Mask is wave-uniform (SGPR) -> byte tests are SCALAR branches;
// sp selects are SALU; weights are statically-indexed REGISTERS (no LDS, no
// latency round-trip in the serial chain). Skipped/included ±0.0 terms are
// bit-exact identities.
// ---------------------------------------------------------------------------
#define FOLD64(mask, WA, WB, BASE, rl, rh)                                   \
    {                                                                        \
        _Pragma("unroll")                                                    \
        for (int b_ = 0; b_ < 8; ++b_) {                                     \
            unsigned int by_ = (unsigned int)(((mask) >> (8 * b_)) & 0xffULL);\
            if (by_) {                                                       \
                _Pragma("unroll")                                            \
                for (int k_ = 0; k_ < 8; ++k_) {                             \
                    float sp_ = ((by_ >> k_) & 1u) ? 1.0f : 0.0f;            \
                    rl = fmaf(sp_, WA[(BASE) + 8 * b_ + k_], rl);            \
                    rh = fmaf(sp_, WB[(BASE) + 8 * b_ + k_], rh);            \
                }                                                            \
            }                                                                \
        }                                                                    \
    }

// ---------------------------------------------------------------------------
// Pass 1: layer-1 recurrence. One wave per sample; lane ln owns neurons
// {ln, 64+ln}. Recurrent weights Wh1 rows {ln, 64+ln} live in 256 VGPRs;
// masks live in SGPRs via ballots. No LDS at all -> per-step cost is the
// executed fmaf chain only.
// ---------------------------------------------------------------------------
extern "C" __global__ void __launch_bounds__(128, 1)
srnn_layer1(const float* __restrict__ D, const float* __restrict__ Wh1,
            const float* __restrict__ bi1, const float* __restrict__ bh1,
            ulonglong2* __restrict__ masks, ulonglong2* __restrict__ state,
            int t0, int Tc, int first)
{
    const int tid = threadIdx.x, w = tid >> 6, ln = tid & 63;
    const int s = 2 * blockIdx.x + w;

    float wl[128], wh[128];                     // Wh1 rows ln, 64+ln
    const float4* r0 = (const float4*)(Wh1 + (size_t)ln * HID);
    const float4* r1 = (const float4*)(Wh1 + (size_t)(64 + ln) * HID);
    #pragma unroll
    for (int q = 0; q < 32; ++q) {
        float4 a = r0[q];
        wl[4 * q + 0] = a.x; wl[4 * q + 1] = a.y;
        wl[4 * q + 2] = a.z; wl[4 * q + 3] = a.w;
        float4 b = r1[q];
        wh[4 * q + 0] = b.x; wh[4 * q + 1] = b.y;
        wh[4 * q + 2] = b.z; wh[4 * q + 3] = b.w;
    }

    const float bil = bi1[ln], bih = bi1[64 + ln];
    const float bhl = bh1[ln], bhh = bh1[64 + ln];
    unsigned long long m0 = 0ULL, m1 = 0ULL;
    if (!first) {
        ulonglong2 st = state[s];
        m0 = rfl64(st.x); m1 = rfl64(st.y);     // keep mask phi uniform
    }

    const float* Drow = D + (size_t)s * Tc * HID;
    float dl[4], dh[4];
    #pragma unroll
    for (int p = 0; p < 4; ++p) {
        int ti = p < Tc ? p : Tc - 1;
        dl[p] = Drow[ti * HID + ln];
        dh[p] = Drow[ti * HID + 64 + ln];
    }

    for (int tt = 0; tt < Tc; tt += 4) {
        #pragma unroll
        for (int u = 0; u < 4; ++u) {
            int t = tt + u;
            if (t >= Tc) break;                       // wave-uniform
            float dense_l = dl[u], dense_h = dh[u];
            int tp = (t + 4 < Tc) ? t + 4 : Tc - 1;   // clamped prefetch
            dl[u] = Drow[tp * HID + ln];
            dh[u] = Drow[tp * HID + 64 + ln];

            float rl = 0.f, rh = 0.f;                 // ascending-j, bit-exact
            FOLD64(m0, wl, wh, 0,  rl, rh);
            FOLD64(m1, wl, wh, 64, rl, rh);

            float hl = ((dense_l + bil) + rl) + bhl;  // reference add order
            float hh = ((dense_h + bih) + rh) + bhh;
            m0 = __ballot(hl >= 1.0f);
            m1 = __ballot(hh >= 1.0f);
            if (ln == 0) {
                ulonglong2 mv; mv.x = m0; mv.y = m1;
                masks[(size_t)s * T_STEPS + (t0 + t)] = mv;
            }
        }
    }
    if (ln == 0) { ulonglong2 st; st.x = m0; st.y = m1; state[s] = st; }
}

// ---------------------------------------------------------------------------
// Pass 1.5 (parallel over all (sample,t) rows): A-term precompute
// D2[row][o] = s1_row @ Wi2^T, ascending-j sparse fold identical to the
// previous in-chain walk (bit-exact). High occupancy (8 waves/block,
// 2 blocks/CU) hides the LDS gather latency across waves.
// ---------------------------------------------------------------------------
extern "C" __global__ void __launch_bounds__(512, 1)
srnn_dense2(const ulonglong2* __restrict__ masks, const float* __restrict__ Wi2,
            float* __restrict__ D2, int t0, int Tc)
{
    extern __shared__ float WT[];              // Wi2^T [129][WPAD]
    const int tid = threadIdx.x, w = tid >> 6, ln = tid & 63;

    stage_wt_s(WT, Wi2, tid, 512);
    __syncthreads();

    const int rows = NS * Tc;
    for (int r = blockIdx.x * 8 + w; r < rows; r += gridDim.x * 8) {
        int s = r / Tc, trel = r - s * Tc;
        ulonglong2 mv = masks[(size_t)s * T_STEPS + t0 + trel];
        unsigned long long m0 = rfl64(mv.x), m1 = rfl64(mv.y);
        float rl = 0.f, rh = 0.f;
        walk8(WT, ln, m0, m1, rl, rh);
        D2[(size_t)r * HID + ln]      = rl;
        D2[(size_t)r * HID + 64 + ln] = rh;
    }
}

// ---------------------------------------------------------------------------
// Pass 2: layer-2 recurrence + output accumulation. A-term streamed from D2;
// Wh2 fold in registers (byte-skip); Wo fold sparse from a small LDS table
// (off the critical chain — result only feeds acc). Chunked with carried
// (p0, p1, acc) state.
// ---------------------------------------------------------------------------
extern "C" __global__ void __launch_bounds__(128, 1)
srnn_layer2(const float* __restrict__ D2, const float* __restrict__ bi2,
            const float* __restrict__ Wh2, const float* __restrict__ bh2,
            const float* __restrict__ Wo,  const float* __restrict__ bo,
            ulonglong2* __restrict__ state2, float* __restrict__ accbuf,
            float* __restrict__ out, int Tc, int first, int last)
{
    __shared__ float WOt[129 * DOUT];          // Wo^T [129][20] (row 128 = 0)
    const int tid = threadIdx.x, w = tid >> 6, ln = tid & 63;
    const int s = 2 * blockIdx.x + w;

    for (int i = tid; i < DOUT * HID / 4; i += 128) {
        int o = i >> 5, jq = i & 31;
        float4 v = ((const float4*)Wo)[i];
        WOt[(4 * jq + 0) * DOUT + o] = v.x; WOt[(4 * jq + 1) * DOUT + o] = v.y;
        WOt[(4 * jq + 2) * DOUT + o] = v.z; WOt[(4 * jq + 3) * DOUT + o] = v.w;
    }
    for (int i = tid; i < DOUT; i += 128) WOt[128 * DOUT + i] = 0.f;

    float wl[128], wh[128];                    // Wh2 rows ln, 64+ln
    const float4* r0 = (const float4*)(Wh2 + (size_t)ln * HID);
    const float4* r1 = (const float4*)(Wh2 + (size_t)(64 + ln) * HID);
    #pragma unroll
    for (int q = 0; q < 32; ++q) {
        float4 a = r0[q];
        wl[4 * q + 0] = a.x; wl[4 * q + 1] = a.y;
        wl[4 * q + 2] = a.z; wl[4 * q + 3] = a.w;
        float4 b = r1[q];
        wh[4 * q + 0] = b.x; wh[4 * q + 1] = b.y;
        wh[4 * q + 2] = b.z; wh[4 * q + 3] = b.w;
    }

    const float bil = bi2[ln], bih = bi2[64 + ln];
    const float bhl = bh2[ln], bhh = bh2[64 + ln];
    const bool  oth = (ln < DOUT);
    const float bol = oth ? bo[ln] : 0.f;

    unsigned long long p0 = 0ULL, p1 = 0ULL;
    float acc = 0.f;
    if (!first) {
        ulonglong2 st = state2[s];
        p0 = rfl64(st.x); p1 = rfl64(st.y);
        if (oth) acc = accbuf[s * DOUT + ln];
    }

    const float* Arow = D2 + (size_t)s * Tc * HID;
    float al[4], ah[4];
    #pragma unroll
    for (int p = 0; p < 4; ++p) {
        int ti = p < Tc ? p : Tc - 1;
        al[p] = Arow[ti * HID + ln];
        ah[p] = Arow[ti * HID + 64 + ln];
    }
    __syncthreads();

    for (int tt = 0; tt < Tc; tt += 4) {
        #pragma unroll
        for (int u = 0; u < 4; ++u) {
            int t = tt + u;
            if (t >= Tc) break;                       // wave-uniform
            float Al = al[u], Ah = ah[u];
            int tp = (t + 4 < Tc) ? t + 4 : Tc - 1;
            al[u] = Arow[tp * HID + ln];
            ah[u] = Arow[tp * HID + 64 + ln];

            float Bl = 0.f, Bh = 0.f;                 // s2 @ Wh2^T (ascending)
            FOLD64(p0, wl, wh, 0,  Bl, Bh);
            FOLD64(p1, wl, wh, 64, Bl, Bh);

            float hl = ((Al + bil) + Bl) + bhl;       // reference add order
            float hh = ((Ah + bih) + Bh) + bhh;
            p0 = __ballot(hl >= 1.0f);
            p1 = __ballot(hh >= 1.0f);

            if (oth) {                                 // s2 @ Wo^T + bo
                float d = 0.f;
                unsigned long long lo = p0, hi = p1;
                int no = __popcll(p0) + __popcll(p1);
                while (no > 0) {
                    int jj[8];
                    #pragma unroll
                    for (int v8 = 0; v8 < 8; ++v8) jj[v8] = next128z(lo, hi);
                    float vv[8];
                    #pragma unroll
                    for (int v8 = 0; v8 < 8; ++v8) vv[v8] = WOt[jj[v8] * DOUT + ln];
                    #pragma unroll
                    for (int v8 = 0; v8 < 8; ++v8) d += vv[v8];
                    no -= 8;
                }
                acc += d;                              // (acc + dot) ...
                acc += bol;                            //  ... + bo
            }
        }
    }
    if (ln == 0) { ulonglong2 st; st.x = p0; st.y = p1; state2[s] = st; }
    if (oth) {
        if (last) out[s * DOUT + ln] = acc / (float)T_STEPS;
        else      accbuf[s * DOUT + ln] = acc;
    }
}

// ---------------------------------------------------------------------------
extern "C" void kernel_launch(void* const* d_in, const int* in_sizes, int n_in,
                              void* d_out, int out_size, void* d_ws, size_t ws_size,
                              hipStream_t stream) {
    const float* x   = (const float*)d_in[0];
    const float* Wi1 = (const float*)d_in[1];
    const float* bi1 = (const float*)d_in[2];
    const float* Wh1 = (const float*)d_in[3];
    const float* bh1 = (const float*)d_in[4];
    const float* Wi2 = (const float*)d_in[5];
    const float* bi2 = (const float*)d_in[6];
    const float* Wh2 = (const float*)d_in[7];
    const float* bh2 = (const float*)d_in[8];
    const float* Wo  = (const float*)d_in[9];
    const float* bo  = (const float*)d_in[10];
    float* out = (float*)d_out;

    // ws layout: [masks 8.192MB][st1 8KB][st2 8KB][acc 40KB][D chunk buffer]
    const size_t mask_bytes = (size_t)NS * T_STEPS * sizeof(ulonglong2);
    const size_t st_bytes   = (size_t)NS * sizeof(ulonglong2);
    const size_t acc_bytes  = (size_t)NS * DOUT * sizeof(float);
    ulonglong2* masks  = (ulonglong2*)d_ws;
    ulonglong2* state  = (ulonglong2*)((char*)d_ws + mask_bytes);
    ulonglong2* state2 = (ulonglong2*)((char*)d_ws + mask_bytes + st_bytes);
    float* accbuf = (float*)((char*)d_ws + mask_bytes + 2 * st_bytes);
    float* D = (float*)((char*)d_ws + mask_bytes + 2 * st_bytes + acc_bytes);

    const size_t head = mask_bytes + 2 * st_bytes + acc_bytes;
    size_t avail = ws_size > head ? ws_size - head : 0;
    const size_t bytes_per_t = (size_t)NS * HID * sizeof(float);  // 256 KB
    long tcmax = (long)(avail / bytes_per_t);
    static const int divs[] = {1000, 500, 250, 200, 125, 100, 50, 40, 25, 20, 10, 8, 5, 4, 2, 1};
    int Tc = 1;
    for (int i = 0; i < 16; ++i) if (divs[i] <= tcmax) { Tc = divs[i]; break; }

    const int lds0 = (128 * XPAD + HID * HID) * (int)sizeof(float);
    const int ldsd2 = (129 * WPAD) * (int)sizeof(float);
    hipFuncSetAttribute((const void*)srnn_dense,
                        hipFuncAttributeMaxDynamicSharedMemorySize, lds0);
    hipFuncSetAttribute((const void*)srnn_dense2,
                        hipFuncAttributeMaxDynamicSharedMemorySize, ldsd2);

    // Phase 1: dense input-term + layer-1 recurrence, chunked over t.
    for (int t0 = 0; t0 < T_STEPS; t0 += Tc) {
        srnn_dense<<<4 * Tc, 512, lds0, stream>>>(x, Wi1, D, t0, Tc);
        srnn_layer1<<<NS / 2, 128, 0, stream>>>(D, Wh1, bi1, bh1, masks, state,
                                                t0, Tc, t0 == 0 ? 1 : 0);
    }
    // Phase 2: parallel A-term (s1 @ Wi2^T) + layer-2 recurrence, chunked.
    for (int t0 = 0; t0 < T_STEPS; t0 += Tc) {
        srnn_dense2<<<512, 512, ldsd2, stream>>>(masks, Wi2, D, t0, Tc);
        srnn_layer2<<<NS / 2, 128, 0, stream>>>(D, bi2, Wh2, bh2, Wo, bo,
                                                state2, accbuf, out, Tc,
                                                t0 == 0 ? 1 : 0,
                                                t0 + Tc >= T_STEPS ? 1 : 0);
    }
}